// Round 1
// baseline (57.535 us; speedup 1.0000x reference)
//
#include <hip/hip_runtime.h>

typedef int int4v __attribute__((ext_vector_type(4)));

// Problem constants
#define BATCH   64
#define HH      56
#define WW      56
#define IN_C    64
#define OUT_C   128
#define NPIX    200704      // 64*56*56
#define KTOT    576         // 3*3*64
#define N_X     12845056    // NPIX * IN_C  (x elements)
#define N_W     73728       // 128*3*3*64
#define N_OUT   25690112    // NPIX * OUT_C

// Conv tiling
#define BLOCK_PIX 64
#define ROWB      592       // 576 + 16 pad: row stride in LDS (bank-safe)

// ---------------------------------------------------------------------------
// Pack x: int32 (sign-extended int8) -> int8, same NHWC layout.
// One thread packs 4 elements (16B read -> 4B write).
__global__ __launch_bounds__(256) void pack_x_kernel(const int4v* __restrict__ x,
                                                     unsigned int* __restrict__ x8) {
    int i = blockIdx.x * 256 + threadIdx.x;   // i < N_X/4 == 3211264 exactly
    int4v v = x[i];
    unsigned int p = (v.x & 0xff) | ((v.y & 0xff) << 8) | ((v.z & 0xff) << 16)
                   | ((unsigned int)(v.w & 0xff) << 24);
    x8[i] = p;
}

// ---------------------------------------------------------------------------
// Pack weights into B-fragment order for mfma_i32_16x16x64_i8:
//   dest byte t = ((kt*8 + nt)*64 + lane)*16 + byte
//   holds W[k][n] with k = kt*64 + (lane>>4)*16 + byte, n = nt*16 + (lane&15)
// Source OHWI flat index = n*576 + k  (since k = (kh*3+kw)*64+ic).
__global__ __launch_bounds__(256) void pack_w_kernel(const int* __restrict__ wgt,
                                                     char* __restrict__ w8) {
    int t = blockIdx.x * 256 + threadIdx.x;   // t < N_W == 73728 exactly
    int byte = t & 15;
    int lane = (t >> 4) & 63;
    int ntk  = t >> 10;
    int nt   = ntk & 7;
    int kt   = ntk >> 3;                      // kt < 9
    int k = kt * 64 + ((lane >> 4) << 4) + byte;
    int n = nt * 16 + (lane & 15);
    w8[t] = (char)wgt[n * KTOT + k];
}

// ---------------------------------------------------------------------------
// MFMA implicit-GEMM conv. Block = 64 pixels x 128 channels, 4 waves.
// Wave wv owns channels [wv*32, wv*32+32) (two 16-wide N-tiles).
__global__ __launch_bounds__(256) void conv_mfma_kernel(const char* __restrict__ x8,
                                                        const char* __restrict__ w8,
                                                        const int* __restrict__ bias,
                                                        int* __restrict__ out) {
    __shared__ char lds[BLOCK_PIX * ROWB];

    const int tid   = threadIdx.x;
    const int lane  = tid & 63;
    const int wv    = tid >> 6;
    const int l15   = lane & 15;
    const int l4    = lane >> 4;
    const int mbase = blockIdx.x * BLOCK_PIX;

    // Load this wave's B fragments (held in registers for the whole block).
    int4v b[9][2];
#pragma unroll
    for (int kt = 0; kt < 9; ++kt) {
#pragma unroll
        for (int ntl = 0; ntl < 2; ++ntl) {
            int nt = wv * 2 + ntl;
            b[kt][ntl] = *(const int4v*)(w8 + ((((kt * 8 + nt) * 64) + lane) << 4));
        }
    }

    // Stage A tile: 64 pixels x 576 bytes (k = (kh*3+kw)*64+ic), zero-padded
    // at image borders. 2304 16-byte chunks, 9 per thread.
#pragma unroll
    for (int it = 0; it < 9; ++it) {
        int c  = tid + it * 256;
        int p  = c / 36;                 // pixel within tile
        int rm = c - p * 36;
        int kh = rm / 12;                // 0..2
        int ck = rm - kh * 12;           // 0..11 : (kw-block 0..2) x (4 x 16B)
        int pg = mbase + p;
        int n  = pg / 3136;
        int r2 = pg - n * 3136;
        int h  = r2 / 56;
        int w  = r2 - h * 56;
        int hx = h + kh - 1;
        int wx = w + (ck >> 2) - 1;
        int4v v = {0, 0, 0, 0};
        if ((unsigned)hx < 56u && (unsigned)wx < 56u) {
            v = *(const int4v*)(x8 + ((((n * 56 + hx) * 56 + wx) << 6) + ((ck & 3) << 4)));
        }
        *(int4v*)(lds + p * ROWB + kh * 192 + (ck << 4)) = v;
    }
    __syncthreads();

    int4v acc[4][2];
#pragma unroll
    for (int mt = 0; mt < 4; ++mt) {
        acc[mt][0] = (int4v){0, 0, 0, 0};
        acc[mt][1] = (int4v){0, 0, 0, 0};
    }

#pragma unroll
    for (int kt = 0; kt < 9; ++kt) {
#pragma unroll
        for (int mt = 0; mt < 4; ++mt) {
            int4v a = *(const int4v*)(lds + (mt * 16 + l15) * ROWB + kt * 64 + (l4 << 4));
            acc[mt][0] = __builtin_amdgcn_mfma_i32_16x16x64_i8(a, b[kt][0], acc[mt][0], 0, 0, 0);
            acc[mt][1] = __builtin_amdgcn_mfma_i32_16x16x64_i8(a, b[kt][1], acc[mt][1], 0, 0, 0);
        }
    }

    // Epilogue: D col = lane&15 (channel), row = 4*(lane>>4)+reg (pixel).
#pragma unroll
    for (int mt = 0; mt < 4; ++mt) {
#pragma unroll
        for (int ntl = 0; ntl < 2; ++ntl) {
            int ch = wv * 32 + ntl * 16 + l15;
            int bv = bias[ch];
#pragma unroll
            for (int r = 0; r < 4; ++r) {
                int pixel = mbase + mt * 16 + l4 * 4 + r;
                out[pixel * OUT_C + ch] = acc[mt][ntl][r] + bv;
            }
        }
    }
}

// ---------------------------------------------------------------------------
// Fallback (only if workspace is too small): direct conv, 1 thread/output.
__global__ __launch_bounds__(256) void conv_naive_kernel(const int* __restrict__ x,
                                                         const int* __restrict__ wgt,
                                                         const int* __restrict__ bias,
                                                         int* __restrict__ out) {
    int idx = blockIdx.x * 256 + threadIdx.x;
    if (idx >= N_OUT) return;
    int ch  = idx & 127;
    int pix = idx >> 7;
    int n  = pix / 3136;
    int r2 = pix - n * 3136;
    int h  = r2 / 56;
    int w  = r2 - h * 56;
    int acc = bias[ch];
    for (int kh = 0; kh < 3; ++kh) {
        int hx = h + kh - 1;
        if ((unsigned)hx >= 56u) continue;
        for (int kw = 0; kw < 3; ++kw) {
            int wx = w + kw - 1;
            if ((unsigned)wx >= 56u) continue;
            const int* xp = x + ((n * 56 + hx) * 56 + wx) * 64;
            const int* wp = wgt + ch * KTOT + (kh * 3 + kw) * 64;
            for (int ic = 0; ic < 64; ++ic) acc += xp[ic] * wp[ic];
        }
    }
    out[idx] = acc;
}

// ---------------------------------------------------------------------------
extern "C" void kernel_launch(void* const* d_in, const int* in_sizes, int n_in,
                              void* d_out, int out_size, void* d_ws, size_t ws_size,
                              hipStream_t stream) {
    const int* x    = (const int*)d_in[0];
    const int* wgt  = (const int*)d_in[1];
    const int* bias = (const int*)d_in[2];
    int* out = (int*)d_out;

    const size_t need = (size_t)N_X + (size_t)N_W;   // 12,918,784 B
    if (ws_size >= need) {
        char* x8 = (char*)d_ws;              // N_X bytes, NHWC int8
        char* w8 = (char*)d_ws + N_X;        // N_W bytes, B-fragment order
        pack_x_kernel<<<N_X / 4 / 256, 256, 0, stream>>>((const int4v*)x, (unsigned int*)x8);
        pack_w_kernel<<<N_W / 256, 256, 0, stream>>>(wgt, w8);
        conv_mfma_kernel<<<NPIX / BLOCK_PIX, 256, 0, stream>>>(x8, w8, bias, out);
    } else {
        conv_naive_kernel<<<(N_OUT + 255) / 256, 256, 0, stream>>>(x, wgt, bias, out);
    }
}